// Round 1
// baseline (184.079 us; speedup 1.0000x reference)
//
#include <hip/hip_runtime.h>

// out[b,i,j] = sum_ch x[b,i,j,ch] * sign(w[((i-ch) mod 32)*32 + (j mod 32)])
// B=256, P=64, C=31, M=32, WS=1024. Rolls cancel on the x index (see derivation).

#define BATCH 256
#define PSZ   64
#define CH    31
#define ROWS_PER_BLOCK 4
#define ROW_FLOATS (PSZ * CH)                         // 1984
#define STAGE_FLOATS (ROWS_PER_BLOCK * ROW_FLOATS)    // 7936
#define STAGE_VEC4 (STAGE_FLOATS / 4)                 // 1984

__global__ __launch_bounds__(256) void codednet_kernel(
    const float* __restrict__ x,
    const float* __restrict__ w,
    float* __restrict__ out)
{
    __shared__ float xs[STAGE_FLOATS];   // 31744 B
    __shared__ float s_lds[1024];        //  4096 B  sign LUT, s[r*32+c]

    const int t   = threadIdx.x;
    const int blk = blockIdx.x;

    // ---- stage sign LUT: 1024 w values, 4 per thread, vectorized ----
    {
        float4 wv = ((const float4*)w)[t];
        float4 sv;
        sv.x = (wv.x > 0.f) ? 1.f : ((wv.x < 0.f) ? -1.f : 0.f);
        sv.y = (wv.y > 0.f) ? 1.f : ((wv.y < 0.f) ? -1.f : 0.f);
        sv.z = (wv.z > 0.f) ? 1.f : ((wv.z < 0.f) ? -1.f : 0.f);
        sv.w = (wv.w > 0.f) ? 1.f : ((wv.w < 0.f) ? -1.f : 0.f);
        ((float4*)s_lds)[t] = sv;
    }

    // ---- stage 4 rows of x (contiguous 31744-byte chunk), float4 coalesced ----
    const float4* __restrict__ xsrc = (const float4*)x + (size_t)blk * STAGE_VEC4;
    float4* xdst = (float4*)xs;
#pragma unroll
    for (int it = 0; it < 8; ++it) {
        int idx = it * 256 + t;
        if (idx < STAGE_VEC4) xdst[idx] = xsrc[idx];
    }
    __syncthreads();

    // ---- each thread: one output pixel ----
    const int r_local = t >> 6;                 // 0..3
    const int j       = t & 63;                 // 0..63
    const int row     = blk * ROWS_PER_BLOCK + r_local;  // b*64 + i
    const int i       = row & 63;
    const int jm      = j & 31;

    const float* __restrict__ xp = &xs[r_local * ROW_FLOATS + j * CH];
    float sum = 0.f;
#pragma unroll
    for (int ch = 0; ch < CH; ++ch) {
        // (i - ch) can be negative; & 31 is correct mod-32 in two's complement
        sum += xp[ch] * s_lds[(((i - ch) & 31) << 5) + jm];
    }

    out[(size_t)row * PSZ + j] = sum;           // = blk*256 + t, coalesced
}

extern "C" void kernel_launch(void* const* d_in, const int* in_sizes, int n_in,
                              void* d_out, int out_size, void* d_ws, size_t ws_size,
                              hipStream_t stream) {
    const float* x = (const float*)d_in[0];   // [256,64,64,31] f32
    const float* w = (const float*)d_in[1];   // [1024] f32
    float* out = (float*)d_out;               // [256,64,64] f32

    const int grid = (BATCH * PSZ) / ROWS_PER_BLOCK;  // 4096
    codednet_kernel<<<grid, 256, 0, stream>>>(x, w, out);
}

// Round 2
// 181.586 us; speedup vs baseline: 1.0137x; 1.0137x over previous
//
#include <hip/hip_runtime.h>

// out[b,i,j] = sum_ch x[b,i,j,ch] * sign(w[((i-ch) mod 32)*32 + (j mod 32)])
// B=256, P=64, C=31. The per-channel fwd/bwd rolls cancel on the x index;
// only the mask row index keeps the (i-ch) dependence. Memory-bound:
// 130 MB read + 4 MB write -> ~21 us floor at 6.3 TB/s.

#define CH 31
#define ROW_FLOATS (64 * CH)            // 1984 floats per staged row
#define RPB 4                           // rows (pixels-rows) per block
#define STAGE_F4 ((RPB * ROW_FLOATS) / 4)  // 1984 float4 = 31744 B

typedef const __attribute__((address_space(1))) void* gptr_t;
typedef __attribute__((address_space(3))) void* lptr_t;

__global__ __launch_bounds__(256) void codednet_kernel(
    const float* __restrict__ x,
    const float* __restrict__ w,
    float* __restrict__ out)
{
    __shared__ float4 xs4[STAGE_F4];    // 31744 B, lane-contiguous order
    __shared__ float  s_lut[1024];      //  4096 B sign LUT

    const int t   = threadIdx.x;
    const int blk = blockIdx.x;

    // ---- async global->LDS staging: 16B/lane, wave-uniform base + lane*16 ----
    const float4* __restrict__ xsrc = (const float4*)x + (size_t)blk * STAGE_F4;
#pragma unroll
    for (int it = 0; it < 7; ++it) {
        const int idx = it * 256 + t;
        __builtin_amdgcn_global_load_lds((gptr_t)(xsrc + idx), (lptr_t)(xs4 + idx), 16, 0, 0);
    }
    if (t < STAGE_F4 - 7 * 256) {       // 192: wave-uniform guard (waves 0-2 full, wave 3 skips)
        const int idx = 7 * 256 + t;
        __builtin_amdgcn_global_load_lds((gptr_t)(xsrc + idx), (lptr_t)(xs4 + idx), 16, 0, 0);
    }

    // ---- sign LUT: 1024 w values, 4/thread ----
    {
        float4 wv = ((const float4*)w)[t];
        float4 sv;
        sv.x = (wv.x > 0.f) ? 1.f : ((wv.x < 0.f) ? -1.f : 0.f);
        sv.y = (wv.y > 0.f) ? 1.f : ((wv.y < 0.f) ? -1.f : 0.f);
        sv.z = (wv.z > 0.f) ? 1.f : ((wv.z < 0.f) ? -1.f : 0.f);
        sv.w = (wv.w > 0.f) ? 1.f : ((wv.w < 0.f) ? -1.f : 0.f);
        ((float4*)s_lut)[t] = sv;
    }
    __syncthreads();   // drains vmcnt (global_load_lds) + lgkmcnt (lut write)

    // ---- one output pixel per thread ----
    const int r_local = t >> 6;                     // 0..3 (wave-uniform)
    const int j       = t & 63;
    const int i       = (blk * RPB + r_local) & 63; // wave-uniform row index
    const int jm      = j & 31;

    const float* __restrict__ xp = (const float*)xs4 + r_local * ROW_FLOATS + j * CH;

    // 4 accumulators to break the serial fma dependency chain
    float a0 = 0.f, a1 = 0.f, a2 = 0.f, a3 = 0.f;
#pragma unroll
    for (int ch = 0; ch < 28; ch += 4) {
        a0 += xp[ch + 0] * s_lut[(((i - ch - 0) & 31) << 5) | jm];
        a1 += xp[ch + 1] * s_lut[(((i - ch - 1) & 31) << 5) | jm];
        a2 += xp[ch + 2] * s_lut[(((i - ch - 2) & 31) << 5) | jm];
        a3 += xp[ch + 3] * s_lut[(((i - ch - 3) & 31) << 5) | jm];
    }
    a0 += xp[28] * s_lut[(((i - 28) & 31) << 5) | jm];
    a1 += xp[29] * s_lut[(((i - 29) & 31) << 5) | jm];
    a2 += xp[30] * s_lut[(((i - 30) & 31) << 5) | jm];

    const float sum = (a0 + a1) + (a2 + a3);
    __builtin_nontemporal_store(sum, &out[(size_t)blk * 256 + t]);  // coalesced
}

extern "C" void kernel_launch(void* const* d_in, const int* in_sizes, int n_in,
                              void* d_out, int out_size, void* d_ws, size_t ws_size,
                              hipStream_t stream) {
    const float* x = (const float*)d_in[0];   // [256,64,64,31] f32
    const float* w = (const float*)d_in[1];   // [1024] f32
    float* out = (float*)d_out;               // [256,64,64] f32

    const int grid = (256 * 64) / RPB;        // 4096 blocks
    codednet_kernel<<<grid, 256, 0, stream>>>(x, w, out);
}